// Round 1
// baseline (89.531 us; speedup 1.0000x reference)
//
#include <hip/hip_runtime.h>
#include <math.h>

#define NPTS   4096
#define NB     8
#define TILE   64
#define NWAVES 4
#define JCHUNK (NPTS / NWAVES)            // 1024
#define INV_H2 (1.0f / (0.03f * 0.03f))   // 1/h^2

__device__ __forceinline__ float med3f(float a, float b, float c) {
#if defined(__has_builtin)
#if __has_builtin(__builtin_amdgcn_fmed3f)
  return __builtin_amdgcn_fmed3f(a, b, c);
#else
  return fminf(c, fmaxf(a, b));
#endif
#else
  return fminf(c, fmaxf(a, b));
#endif
}

// Scan LDS points [lo,hi), maintaining sorted 4-smallest t0<=t1<=t2<=t3.
// Branchless insert: 1 v_min + 3 v_med3 per element.
template <bool CHECK>
__device__ __forceinline__ void scan_range(const float2* __restrict__ sxy,
                                           const float* __restrict__ sz,
                                           int lo, int hi, int self,
                                           float xi, float yi, float zi,
                                           float& t0, float& t1, float& t2, float& t3) {
#pragma unroll 8
  for (int j = lo; j < hi; ++j) {
    float2 xy = sxy[j];
    float zz  = sz[j];
    float dx = xy.x - xi;
    float dy = xy.y - yi;
    float dz = zz   - zi;
    float d = fmaf(dx, dx, fmaf(dy, dy, dz * dz));
    if (CHECK) d = (j == self) ? 3.0e38f : d;  // exclude self (only one wave segment)
    // sorted insert, keep 4 smallest (order matters: high -> low uses old values)
    t3 = med3f(t2, d, t3);
    t2 = med3f(t1, d, t2);
    t1 = med3f(t0, d, t1);
    t0 = fminf(t0, d);
  }
}

// lowest-4 (sorted ascending) of two ascending 4-lists: bitonic ladder + merge.
__device__ __forceinline__ void merge4(float a0, float a1, float a2, float a3,
                                       float b0, float b1, float b2, float b3,
                                       float& o0, float& o1, float& o2, float& o3) {
  float L0 = fminf(a0, b3), L1 = fminf(a1, b2), L2 = fminf(a2, b1), L3 = fminf(a3, b0);
  float e0 = fminf(L0, L2), e2 = fmaxf(L0, L2);
  float e1 = fminf(L1, L3), e3 = fmaxf(L1, L3);
  o0 = fminf(e0, e1); o1 = fmaxf(e0, e1);
  o2 = fminf(e2, e3); o3 = fmaxf(e2, e3);
}

__global__ __launch_bounds__(256)
void repulsion_kernel(const float* __restrict__ pc, float* __restrict__ out) {
  __shared__ float2 sxy[NPTS];                 // 32 KB
  __shared__ float  sz[NPTS];                  // 16 KB
  __shared__ float4 cand4[NWAVES * TILE];      //  4 KB

  const int blk  = blockIdx.x;
  const int b    = blk >> 6;      // / (NPTS/TILE)
  const int tile = blk & 63;
  const int tid  = threadIdx.x;
  const float* base = pc + (size_t)b * NPTS * 3;

  // Stage this batch's 4096 points into LDS (48 KB, read via L1/L2).
  for (int k = tid; k < NPTS; k += 256) {
    float x = base[3 * k + 0];
    float y = base[3 * k + 1];
    float z = base[3 * k + 2];
    sxy[k] = make_float2(x, y);
    sz[k]  = z;
  }
  __syncthreads();

  const int w    = tid >> 6;      // wave index = j-quarter
  const int lane = tid & 63;      // point within tile
  const int self = tile * TILE + lane;

  float2 pxy = sxy[self];
  const float xi = pxy.x, yi = pxy.y, zi = sz[self];

  const float INF = 3.0e38f;
  float t0 = INF, t1 = INF, t2 = INF, t3 = INF;

  const int j0 = w * JCHUNK;
  const int selfwave = tile >> 4;  // (tile*64)/1024 — wave whose quarter holds the tile
  if (w == selfwave) {
    const int s0 = tile * TILE;
    scan_range<false>(sxy, sz, j0, s0, self, xi, yi, zi, t0, t1, t2, t3);
    scan_range<true >(sxy, sz, s0, s0 + TILE, self, xi, yi, zi, t0, t1, t2, t3);
    scan_range<false>(sxy, sz, s0 + TILE, j0 + JCHUNK, self, xi, yi, zi, t0, t1, t2, t3);
  } else {
    scan_range<false>(sxy, sz, j0, j0 + JCHUNK, self, xi, yi, zi, t0, t1, t2, t3);
  }

  cand4[w * TILE + lane] = make_float4(t0, t1, t2, t3);
  __syncthreads();

  if (tid < 64) {
    float4 A = cand4[0 * TILE + lane];
    float4 B = cand4[1 * TILE + lane];
    float4 C = cand4[2 * TILE + lane];
    float4 D = cand4[3 * TILE + lane];
    float ab0, ab1, ab2, ab3, cd0, cd1, cd2, cd3;
    merge4(A.x, A.y, A.z, A.w, B.x, B.y, B.z, B.w, ab0, ab1, ab2, ab3);
    merge4(C.x, C.y, C.z, C.w, D.x, D.y, D.z, D.w, cd0, cd1, cd2, cd3);
    // final: 4 smallest of the two sorted 4-lists (set suffices, no sort needed)
    float m0 = fminf(ab0, cd3);
    float m1 = fminf(ab1, cd2);
    float m2 = fminf(ab2, cd1);
    float m3 = fminf(ab3, cd0);

    float s = 0.0f;
    s -= m0 * expf(-m0 * INV_H2);
    s -= m1 * expf(-m1 * INV_H2);
    s -= m2 * expf(-m2 * INV_H2);
    s -= m3 * expf(-m3 * INV_H2);

    // wave-level reduction over the 64 merge lanes
    for (int off = 32; off > 0; off >>= 1) s += __shfl_down(s, off);
    if (lane == 0) atomicAdd(out, s);
  }
}

extern "C" void kernel_launch(void* const* d_in, const int* in_sizes, int n_in,
                              void* d_out, int out_size, void* d_ws, size_t ws_size,
                              hipStream_t stream) {
  const float* pc = (const float*)d_in[0];
  float* out = (float*)d_out;
  // d_out is poisoned before every launch — zero it on-stream (graph-capturable).
  hipMemsetAsync(out, 0, sizeof(float), stream);
  repulsion_kernel<<<dim3(NB * (NPTS / TILE)), dim3(256), 0, stream>>>(pc, out);
}

// Round 2
// 82.166 us; speedup vs baseline: 1.0896x; 1.0896x over previous
//
#include <hip/hip_runtime.h>
#include <math.h>

#define NPTS   4096
#define NB     8
#define TILE   64
#define NWAVES 8
#define BLK    (NWAVES * 64)              // 512 threads
#define JCHUNK (NPTS / NWAVES)            // 512
#define INV_H2 (1.0f / (0.03f * 0.03f))   // 1/h^2

__device__ __forceinline__ float med3f(float a, float b, float c) {
#if defined(__has_builtin)
#if __has_builtin(__builtin_amdgcn_fmed3f)
  return __builtin_amdgcn_fmed3f(a, b, c);
#else
  return fminf(c, fmaxf(a, b));   // equivalent to med3 when a<=c (our usage)
#endif
#else
  return fminf(c, fmaxf(a, b));
#endif
}

// Scan LDS points [lo,hi): d = sq_i + (sq_j - 2*p_i.p_j) via premultiplied
// m = -2*p_i  ->  4 VALU (3 fma + 1 add) per pair, then 4-op sorted insert.
template <bool CHECK>
__device__ __forceinline__ void scan_range(const float4* __restrict__ sP,
                                           int lo, int hi, int self,
                                           float mx, float my, float mz, float sqi,
                                           float& t0, float& t1, float& t2, float& t3) {
#pragma unroll 8
  for (int j = lo; j < hi; ++j) {
    float4 q = sP[j];                         // ds_read_b128, wave-uniform addr (broadcast)
    float t = fmaf(mz, q.z, q.w);             // q.w = ||p_j||^2
    t = fmaf(my, q.y, t);
    t = fmaf(mx, q.x, t);
    float d = t + sqi;
    if (CHECK) d = (j == self) ? 3.0e38f : d; // exclude self (one 64-iter segment only)
    // sorted insert into t0<=t1<=t2<=t3 (uses previous-iteration values; 4 indep ops)
    t3 = med3f(t2, d, t3);
    t2 = med3f(t1, d, t2);
    t1 = med3f(t0, d, t1);
    t0 = fminf(t0, d);
  }
}

// lowest-4 (ascending) of two ascending 4-lists.
__device__ __forceinline__ void merge4(float a0, float a1, float a2, float a3,
                                       float b0, float b1, float b2, float b3,
                                       float& o0, float& o1, float& o2, float& o3) {
  float L0 = fminf(a0, b3), L1 = fminf(a1, b2), L2 = fminf(a2, b1), L3 = fminf(a3, b0);
  float e0 = fminf(L0, L2), e2 = fmaxf(L0, L2);
  float e1 = fminf(L1, L3), e3 = fmaxf(L1, L3);
  o0 = fminf(e0, e1); o1 = fmaxf(e0, e1);
  o2 = fminf(e2, e3); o3 = fmaxf(e2, e3);
}

__global__ __launch_bounds__(BLK)
void repulsion_kernel(const float* __restrict__ pc, float* __restrict__ out) {
  __shared__ float4 sP[NPTS];                  // 64 KB: x,y,z,||p||^2
  __shared__ float4 cand4[NWAVES * TILE];      //  8 KB

  const int blk  = blockIdx.x;
  const int b    = blk >> 6;      // / (NPTS/TILE)
  const int tile = blk & 63;
  const int tid  = threadIdx.x;
  const float* base = pc + (size_t)b * NPTS * 3;
  const float4* pcv = (const float4*)base;     // 3072 float4 per batch (16B-aligned)

  // Stage batch into LDS: 3 float4 global reads -> 4 points each.
  for (int g = tid; g < NPTS / 4; g += BLK) {
    float4 a = pcv[3 * g + 0];
    float4 c = pcv[3 * g + 1];
    float4 e = pcv[3 * g + 2];
    float x0 = a.x, y0 = a.y, z0 = a.z;
    float x1 = a.w, y1 = c.x, z1 = c.y;
    float x2 = c.z, y2 = c.w, z2 = e.x;
    float x3 = e.y, y3 = e.z, z3 = e.w;
    sP[4 * g + 0] = make_float4(x0, y0, z0, fmaf(x0, x0, fmaf(y0, y0, z0 * z0)));
    sP[4 * g + 1] = make_float4(x1, y1, z1, fmaf(x1, x1, fmaf(y1, y1, z1 * z1)));
    sP[4 * g + 2] = make_float4(x2, y2, z2, fmaf(x2, x2, fmaf(y2, y2, z2 * z2)));
    sP[4 * g + 3] = make_float4(x3, y3, z3, fmaf(x3, x3, fmaf(y3, y3, z3 * z3)));
  }
  __syncthreads();

  const int w    = tid >> 6;      // wave index = j-eighth
  const int lane = tid & 63;      // point within tile
  const int self = tile * TILE + lane;

  float4 me = sP[self];
  const float mx = -2.0f * me.x, my = -2.0f * me.y, mz = -2.0f * me.z;
  const float sqi = me.w;

  const float INF = 3.0e38f;
  float t0 = INF, t1 = INF, t2 = INF, t3 = INF;

  const int j0 = w * JCHUNK;
  const int selfwave = tile >> 3;  // (tile*64)/512 — wave whose chunk holds the tile
  if (w == selfwave) {
    const int s0 = tile * TILE;
    scan_range<false>(sP, j0, s0, self, mx, my, mz, sqi, t0, t1, t2, t3);
    scan_range<true >(sP, s0, s0 + TILE, self, mx, my, mz, sqi, t0, t1, t2, t3);
    scan_range<false>(sP, s0 + TILE, j0 + JCHUNK, self, mx, my, mz, sqi, t0, t1, t2, t3);
  } else {
    scan_range<false>(sP, j0, j0 + JCHUNK, self, mx, my, mz, sqi, t0, t1, t2, t3);
  }

  cand4[w * TILE + lane] = make_float4(t0, t1, t2, t3);
  __syncthreads();

  if (tid < 64) {
    float4 A = cand4[0 * TILE + lane];
    float4 B = cand4[1 * TILE + lane];
    float4 C = cand4[2 * TILE + lane];
    float4 D = cand4[3 * TILE + lane];
    float4 E = cand4[4 * TILE + lane];
    float4 F = cand4[5 * TILE + lane];
    float4 G = cand4[6 * TILE + lane];
    float4 H4 = cand4[7 * TILE + lane];
    float ab0, ab1, ab2, ab3, cd0, cd1, cd2, cd3;
    float ef0, ef1, ef2, ef3, gh0, gh1, gh2, gh3;
    merge4(A.x, A.y, A.z, A.w, B.x, B.y, B.z, B.w, ab0, ab1, ab2, ab3);
    merge4(C.x, C.y, C.z, C.w, D.x, D.y, D.z, D.w, cd0, cd1, cd2, cd3);
    merge4(E.x, E.y, E.z, E.w, F.x, F.y, F.z, F.w, ef0, ef1, ef2, ef3);
    merge4(G.x, G.y, G.z, G.w, H4.x, H4.y, H4.z, H4.w, gh0, gh1, gh2, gh3);
    float u0, u1, u2, u3, v0, v1, v2, v3;
    merge4(ab0, ab1, ab2, ab3, cd0, cd1, cd2, cd3, u0, u1, u2, u3);
    merge4(ef0, ef1, ef2, ef3, gh0, gh1, gh2, gh3, v0, v1, v2, v3);
    // final: the 4-smallest set of two sorted 4-lists (no sort needed)
    float m0 = fminf(u0, v3);
    float m1 = fminf(u1, v2);
    float m2 = fminf(u2, v1);
    float m3 = fminf(u3, v0);

    float s = 0.0f;
    s -= m0 * expf(-m0 * INV_H2);
    s -= m1 * expf(-m1 * INV_H2);
    s -= m2 * expf(-m2 * INV_H2);
    s -= m3 * expf(-m3 * INV_H2);

    for (int off = 32; off > 0; off >>= 1) s += __shfl_down(s, off);
    if (lane == 0) atomicAdd(out, s);
  }
}

extern "C" void kernel_launch(void* const* d_in, const int* in_sizes, int n_in,
                              void* d_out, int out_size, void* d_ws, size_t ws_size,
                              hipStream_t stream) {
  const float* pc = (const float*)d_in[0];
  float* out = (float*)d_out;
  hipMemsetAsync(out, 0, sizeof(float), stream);
  repulsion_kernel<<<dim3(NB * (NPTS / TILE)), dim3(BLK), 0, stream>>>(pc, out);
}